// Round 12
// baseline (162.068 us; speedup 1.0000x reference)
//
#include <hip/hip_runtime.h>
#include <hip/hip_bf16.h>
#include <stdint.h>

// Problem constants (B,H,W,C = 4,64,64,256)
#define NN 4096        // H*W
#define CC 256
#define DD 32          // C/8
#define CHW 17408      // u16 per hhT chunk: 2(ks) * 17(ct) * 64(lane) * 8(j)
#define NCT 9          // staged ct tiles per channel-split: 8 channel tiles + ones

typedef short    bf16x8 __attribute__((ext_vector_type(8)));
typedef _Float16 f16x8  __attribute__((ext_vector_type(8)));
typedef float    f32x4  __attribute__((ext_vector_type(4)));
typedef unsigned short u16x4 __attribute__((ext_vector_type(4)));

__device__ __forceinline__ unsigned short bf16_rne(float x) {
    union { float f; unsigned int u; } v; v.f = x;
    unsigned int u = v.u;
    return (unsigned short)((u + 0x7FFFu + ((u >> 16) & 1u)) >> 16);
}
__device__ __forceinline__ float bf16f(unsigned short h) {
    union { float f; unsigned int u; } v; v.u = ((unsigned int)h) << 16; return v.f;
}
__device__ __forceinline__ unsigned short f16_bits(float x) {
    union { _Float16 h; unsigned short u; } v; v.h = (_Float16)x;
    return v.u;
}
// hardware packed f32->bf16 RNE convert (no builtin on gfx950; T12 recipe)
__device__ __forceinline__ unsigned int cvt_pk_bf16(float lo, float hi) {
    unsigned int r;
    asm("v_cvt_pk_bf16_f32 %0, %1, %2" : "=v"(r) : "v"(lo), "v"(hi));
    return r;
}
// async global->LDS, 16B per lane; LDS dest = wave-uniform base + lane*16
__device__ __forceinline__ void load_lds16(const unsigned short* g, unsigned short* l) {
    __builtin_amdgcn_global_load_lds(
        (const __attribute__((address_space(1))) unsigned int*)g,
        (__attribute__((address_space(3))) unsigned int*)l, 16, 0, 0);
}

// ---------------------------------------------------------------------------
// Kernel 0: pre-convert weights to bf16, chunk-tiled Wst[ks(8)][row(384)][k(32)].
// rows 0..255 = Wh col (hi), 256..319 = Wf/Wg hi, 320..383 = Wf/Wg lo.
// ---------------------------------------------------------------------------
__global__ __launch_bounds__(256) void prep_kernel(
    const float* __restrict__ Wf, const float* __restrict__ Wg,
    const float* __restrict__ Wh, unsigned short* __restrict__ Wst)
{
    int id  = blockIdx.x * 256 + threadIdx.x;   // grid 384 -> 98304
    int ks  = id / 12288;
    int rem = id - ks * 12288;
    int row = rem >> 5;
    int k   = ks * 32 + (rem & 31);
    unsigned short outv;
    if (row < 256) {
        outv = bf16_rne(Wh[(size_t)k * CC + row]);
    } else if (row < 320) {
        int d = row - 256;
        float v = (d < 32) ? Wf[(size_t)k * DD + d] : Wg[(size_t)k * DD + (d - 32)];
        outv = bf16_rne(v);
    } else {
        int d = row - 320;
        float v = (d < 32) ? Wf[(size_t)k * DD + d] : Wg[(size_t)k * DD + (d - 32)];
        unsigned short h = bf16_rne(v);
        outv = bf16_rne(v - bf16f(h));
    }
    Wst[id] = outv;
}

// ---------------------------------------------------------------------------
// Kernel 1: MFMA projections. MINIMAL-DIFF bisect of the R10 failure:
// structure is verbatim R9 (x staged hi/lo in LDS, both per-ks
// __syncthreads in their original positions, bh/bl as scalar temporaries
// loaded inside the t-loop) EXCEPT the W B-fragments are read directly from
// global Wst (L2-resident, 192KB) at the exact addresses the R9 LDS copy
// held: WT[wrow*40+quad*8] == Wst[ks*12288 + wrow*32 + quad*8] (slot algebra:
// slot=wrow*5+quad, row=slot/5=wrow, g=slot%5=quad). The 30KB/ks W staging
// DMA is deleted. ONE variable vs R9; values bit-identical.
// (R10's barrier-free + prefetch-array variant NaN'd; since its ks loop has
// no cross-thread deps, that points at codegen, not a race — this version
// keeps R9's barrier skeleton and register shape.)
// ---------------------------------------------------------------------------
__global__ __launch_bounds__(256, 2) void proj_kernel(
    const float* __restrict__ x,
    const float* __restrict__ bfv, const float* __restrict__ bgv,
    const float* __restrict__ bhv,
    const unsigned short* __restrict__ Wst,
    unsigned short* __restrict__ f16b, unsigned short* __restrict__ g16b,
    unsigned short* __restrict__ hhT)
{
    const int tid  = threadIdx.x;
    const int lane = tid & 63;
    const int wv   = tid >> 6;
    const int col  = lane & 15;
    const int quad = lane >> 4;
    const int tok0 = blockIdx.x * 32;      // 32 | 4096 -> no batch straddle
    const int b    = tok0 >> 12;

    __shared__ __align__(16) unsigned short xh[32 * 272];   // pitch 272 u16 (544B)
    __shared__ __align__(16) unsigned short xl[32 * 272];

    // ---- stage x (hi/lo) ----
    #pragma unroll
    for (int it = 0; it < 8; ++it) {
        int idx = it * 1024 + tid * 4;
        float4 v = *(const float4*)(x + (size_t)tok0 * CC + idx);
        int tok = idx >> 8, k = idx & 255;
        unsigned short h0 = bf16_rne(v.x), h1 = bf16_rne(v.y),
                       h2 = bf16_rne(v.z), h3 = bf16_rne(v.w);
        uint2 wh_, wl_;
        wh_.x = (unsigned int)h0 | ((unsigned int)h1 << 16);
        wh_.y = (unsigned int)h2 | ((unsigned int)h3 << 16);
        wl_.x = (unsigned int)bf16_rne(v.x - bf16f(h0)) |
                ((unsigned int)bf16_rne(v.y - bf16f(h1)) << 16);
        wl_.y = (unsigned int)bf16_rne(v.z - bf16f(h2)) |
                ((unsigned int)bf16_rne(v.w - bf16f(h3)) << 16);
        *(uint2*)&xh[tok * 272 + k] = wh_;
        *(uint2*)&xl[tok * 272 + k] = wl_;
    }

    // ---- acc init with bias ----
    f32x4 acc[5][2];
    #pragma unroll
    for (int t = 0; t < 5; ++t) {
        int tl = wv * 5 + t;
        float bias;
        if (tl < 16) bias = bhv[tl * 16 + col];
        else { int fd = (tl - 16) * 16 + col;
               bias = (fd < 32) ? bfv[fd] : bgv[fd - 32]; }
        acc[t][0] = (f32x4){bias, bias, bias, bias};
        acc[t][1] = (f32x4){bias, bias, bias, bias};
    }

    for (int ks = 0; ks < 8; ++ks) {
        __syncthreads();   // R9 barrier #1 position (at ks==0 guards x staging)

        // ---- A fragments from LDS ----
        bf16x8 ah[2], al[2];
        #pragma unroll
        for (int mt = 0; mt < 2; ++mt) {
            ah[mt] = *(const bf16x8*)&xh[(mt * 16 + col) * 272 + ks * 32 + quad * 8];
            al[mt] = *(const bf16x8*)&xl[(mt * 16 + col) * 272 + ks * 32 + quad * 8];
        }

        const unsigned short* wb = Wst + (size_t)ks * 12288;
        #pragma unroll
        for (int t = 0; t < 5; ++t) {
            int tl = wv * 5 + t;
            int wrow = (tl < 16) ? (tl * 16 + col) : (256 + (tl - 16) * 16 + col);
            bf16x8 bh = *(const bf16x8*)(wb + (size_t)wrow * 32 + quad * 8);
            #pragma unroll
            for (int mt = 0; mt < 2; ++mt) {
                acc[t][mt] = __builtin_amdgcn_mfma_f32_16x16x32_bf16(ah[mt], bh, acc[t][mt], 0, 0, 0);
                acc[t][mt] = __builtin_amdgcn_mfma_f32_16x16x32_bf16(al[mt], bh, acc[t][mt], 0, 0, 0);
            }
            if (tl >= 16) {   // wave-uniform
                bf16x8 bl = *(const bf16x8*)(wb + (size_t)(wrow + 64) * 32 + quad * 8);
                #pragma unroll
                for (int mt = 0; mt < 2; ++mt)
                    acc[t][mt] = __builtin_amdgcn_mfma_f32_16x16x32_bf16(ah[mt], bl, acc[t][mt], 0, 0, 0);
            }
        }
        __syncthreads();   // R9 barrier #2 position
    }

    // ---- epilogue (fragment-order hhT writes; f/g as fp16) ----
    const int ks_h = (tok0 & 63) >> 5;       // 0 or 1
    const int kc   = (tok0 & 4095) >> 6;
    const size_t tbase = ((size_t)(b * 64 + kc)) * CHW;
    #pragma unroll
    for (int t = 0; t < 5; ++t) {
        int tl = wv * 5 + t;
        if (tl < 16) {
            #pragma unroll
            for (int mt = 0; mt < 2; ++mt) {
                int qk = mt * 2 + (quad >> 1);
                int jb = (quad & 1) * 4;
                uint2 w;
                w.x = (unsigned int)bf16_rne(acc[t][mt][0]) | ((unsigned int)bf16_rne(acc[t][mt][1]) << 16);
                w.y = (unsigned int)bf16_rne(acc[t][mt][2]) | ((unsigned int)bf16_rne(acc[t][mt][3]) << 16);
                *(uint2*)&hhT[tbase + (size_t)(((ks_h * 17 + tl) * 64) + qk * 16 + col) * 8 + jb] = w;
            }
        } else {
            int fd = (tl - 16) * 16 + col;
            unsigned short* dst = (fd < 32) ? f16b : g16b;
            int d = fd & 31;
            #pragma unroll
            for (int mt = 0; mt < 2; ++mt)
                #pragma unroll
                for (int r = 0; r < 4; ++r) {
                    int tok = tok0 + mt * 16 + quad * 4 + r;
                    dst[(size_t)tok * DD + d] = f16_bits(acc[t][mt][r]);
                }
        }
    }
    // ones-tile (ct=16): channel 256+ck -> 1.0 iff ck==0; this block's ks half
    #pragma unroll
    for (int it = 0; it < 2; ++it) {
        int e = tid + it * 256;              // 512 entries: [qk(4)][ck(16)][j(8)]
        int j = e & 7, ck = (e >> 3) & 15, qk = e >> 7;
        hhT[tbase + (size_t)(((ks_h * 17 + 16) * 64) + qk * 16 + ck) * 8 + j] =
            (ck == 0) ? (unsigned short)0x3F80 : (unsigned short)0;
    }
}

// ---------------------------------------------------------------------------
// Kernel 2: fused attention (UNCHANGED from R9 -- last-known-good).
// Fixed-max softmax (M=40), 4-way split-K x 2-way channel split, 1024 blocks.
// 32-key half-steps, counted vmcnt(3|2) + sched_barrier fences, in-register P
// (swapped QK^T + key permutation), hw cvt_pk, -40 folded into QK C-init,
// setprio'd PV, bf16 partial-O.
// ---------------------------------------------------------------------------
__global__ __launch_bounds__(256, 4) void attn_kernel(
    const unsigned short* __restrict__ g16b,
    const unsigned short* __restrict__ f16b,
    const unsigned short* __restrict__ hhT,    // [b][kc][ks][ct][lane][j]
    unsigned short* __restrict__ Ob0,          // bf16 partials [B*NN][CC]
    unsigned short* __restrict__ Ob1,
    unsigned short* __restrict__ Ob2,
    unsigned short* __restrict__ Ob3,
    float* __restrict__ lbuf)                  // [4][B*NN]
{
    const int tid  = threadIdx.x;
    const int lane = tid & 63;
    const int wv   = tid >> 6;             // 0..3
    const int col  = lane & 15;
    const int quad = lane >> 4;
    const int bid  = blockIdx.x;
    const int csp  = bid & 1;              // channel split 0..1
    const int sp   = (bid >> 1) & 3;       // key split 0..3
    const int b    = (bid >> 3) & 3;       // batch
    const int qblk = bid >> 5;             // 0..31
    const int q0   = qblk * 128 + wv * 32; // wave's 32-query base
    const int kcb  = sp * 16;              // this split's chunk range

    __shared__ __align__(16) unsigned short hbuf[2][NCT * 512];  // 2 x 9 KiB

    const unsigned short* fb16 = f16b + (size_t)b * NN * DD;
    const unsigned short* hb   = hhT + (size_t)b * 64 * CHW;

    f16x8 a_g[2];
    #pragma unroll
    for (int a = 0; a < 2; ++a)
        a_g[a] = *(const f16x8*)(g16b + ((size_t)(b * NN + q0 + a * 16 + col)) * DD + quad * 8);

    // permuted key offset within a 32-key half-step for the f A-fragment:
    // M-slot col of tile ktl holds key (col>>2)*8 + ktl*4 + (col&3)
    const int kpermu = (col >> 2) * 8 + (col & 3);

    const f32x4 m40 = {-40.f, -40.f, -40.f, -40.f};   // folded softmax shift
    f32x4 acc[2][NCT];
    #pragma unroll
    for (int a = 0; a < 2; ++a)
        #pragma unroll
        for (int i = 0; i < NCT; ++i) acc[a][i] = (f32x4){0.f, 0.f, 0.f, 0.f};

    // ---- stage half-step 0 (chunk kcb, key-half 0): 9 ct slots over 4 waves ----
    {
        const unsigned short* tile = hb + (size_t)kcb * CHW;   // ks = 0
        #pragma unroll
        for (int t = 0; t < 3; ++t) {
            int s = wv + t * 4;
            if (s >= NCT) break;
            int ct = (s < 8) ? (csp * 8 + s) : 16;
            load_lds16(tile + (size_t)ct * 512 + lane * 8, &hbuf[0][s * 512]);
        }
    }
    __syncthreads();   // prologue: full drain once (buf0 ready)

    // 16 chunks x 2 key-halves = 32 half-steps of 32 keys each
    for (int hs = 0; hs < 32; ++hs) {
        const int nb = hs & 1;

        // ---- async stage next half-step into other buffer ----
        if (hs + 1 < 32) {
            const int kc = kcb + ((hs + 1) >> 1);
            const int ks = (hs + 1) & 1;
            const unsigned short* tile = hb + (size_t)kc * CHW + (size_t)(ks * 17) * 512;
            #pragma unroll
            for (int t = 0; t < 3; ++t) {
                int s = wv + t * 4;
                if (s >= NCT) break;
                int ct = (s < 8) ? (csp * 8 + s) : 16;
                load_lds16(tile + (size_t)ct * 512 + lane * 8, &hbuf[nb ^ 1][s * 512]);
            }
        }

        const int kk0 = kcb * 64 + hs * 32;   // this half-step's 32-key base

        // ---- QK^T swapped (fp16), C-init = -40: C[key-slot][query]; keys
        //      permuted so lane (quad,col) gets keys quad*8+ktl*4+r, query col ----
        f32x4 s_t[2][2];
        #pragma unroll
        for (int ktl = 0; ktl < 2; ++ktl) {
            f16x8 af_ = *(const f16x8*)(fb16 +
                (size_t)(kk0 + kpermu + ktl * 4) * DD + quad * 8);
            #pragma unroll
            for (int a = 0; a < 2; ++a)
                s_t[ktl][a] = __builtin_amdgcn_mfma_f32_16x16x32_f16(af_, a_g[a], m40, 0, 0, 0);
        }

        // ---- p = exp(s): hw-packed f32->bf16, PV A-frags in-register ----
        bf16x8 a_p[2];
        #pragma unroll
        for (int a = 0; a < 2; ++a) {
            union { unsigned int u[4]; bf16x8 v; } cv;
            #pragma unroll
            for (int ktl = 0; ktl < 2; ++ktl) {
                float e0 = __expf(s_t[ktl][a][0]);
                float e1 = __expf(s_t[ktl][a][1]);
                float e2 = __expf(s_t[ktl][a][2]);
                float e3 = __expf(s_t[ktl][a][3]);
                cv.u[ktl * 2 + 0] = cvt_pk_bf16(e0, e1);
                cv.u[ktl * 2 + 1] = cvt_pk_bf16(e2, e3);
            }
            a_p[a] = cv.v;
        }

        // ---- barrier #1: previous stage retired in every wave; this hs's
        //      prefetch (3 loads wv0 / 2 loads wv1-3) stays outstanding ----
        __builtin_amdgcn_sched_barrier(0);
        if (wv == 0) asm volatile("s_waitcnt vmcnt(3)" ::: "memory");
        else         asm volatile("s_waitcnt vmcnt(2)" ::: "memory");
        __builtin_amdgcn_s_barrier();
        __builtin_amdgcn_sched_barrier(0);

        // ---- PV over this csp's 9 staged ct tiles; B-frag feeds both atiles ----
        __builtin_amdgcn_s_setprio(1);
        #pragma unroll
        for (int s = 0; s < NCT; ++s) {
            bf16x8 bh = *(const bf16x8*)&hbuf[nb][(s * 64 + lane) * 8];
            acc[0][s] = __builtin_amdgcn_mfma_f32_16x16x32_bf16(a_p[0], bh, acc[0][s], 0, 0, 0);
            acc[1][s] = __builtin_amdgcn_mfma_f32_16x16x32_bf16(a_p[1], bh, acc[1][s], 0, 0, 0);
        }
        __builtin_amdgcn_s_setprio(0);

        // ---- barrier #2: overwrite guard for the buffer re-staged next iter ----
        __builtin_amdgcn_sched_barrier(0);
        __builtin_amdgcn_s_barrier();
        __builtin_amdgcn_sched_barrier(0);
    }

    // ---- epilogue: store bf16 partial O (this csp's 128 channels) and l ----
    unsigned short* Obufs[4] = {Ob0, Ob1, Ob2, Ob3};
    unsigned short* Op = Obufs[sp];
    #pragma unroll
    for (int a = 0; a < 2; ++a) {
        const size_t obase = (size_t)(b * NN + q0 + a * 16) * CC;
        #pragma unroll
        for (int s = 0; s < 8; ++s) {
            const int ch = (csp * 8 + s) * 16 + col;
            #pragma unroll
            for (int r = 0; r < 4; ++r)
                Op[obase + (size_t)(quad * 4 + r) * CC + ch] = bf16_rne(acc[a][s][r]);
        }
        if (csp == 0 && col == 0) {   // l from the ones tile; csp0 owns it
            #pragma unroll
            for (int r = 0; r < 4; ++r)
                lbuf[sp * (4 * NN) + b * NN + q0 + a * 16 + quad * 4 + r] = acc[a][8][r];
        }
    }
}

// ---------------------------------------------------------------------------
// Kernel 3: out = x + (Ob0+Ob1+Ob2+Ob3) / (l0+l1+l2+l3).  bf16 partials.
// ---------------------------------------------------------------------------
__global__ __launch_bounds__(256) void reduce_kernel(
    const float* __restrict__ x,
    const unsigned short* __restrict__ Ob0, const unsigned short* __restrict__ Ob1,
    const unsigned short* __restrict__ Ob2, const unsigned short* __restrict__ Ob3,
    const float* __restrict__ lbuf, float* __restrict__ out)
{
    int id = blockIdx.x * 256 + threadIdx.x;   // grid 4096 -> 1048576
    int q  = id >> 6;                          // token row (B*NN)
    int c4 = (id & 63) * 4;
    size_t base = (size_t)q * CC + c4;
    float inv = 1.0f / (lbuf[q] + lbuf[4 * NN + q] + lbuf[8 * NN + q] + lbuf[12 * NN + q]);
    u16x4 p0 = *(const u16x4*)(Ob0 + base);
    u16x4 p1 = *(const u16x4*)(Ob1 + base);
    u16x4 p2 = *(const u16x4*)(Ob2 + base);
    u16x4 p3 = *(const u16x4*)(Ob3 + base);
    float4 xv = *(const float4*)(x + base);
    float4 r;
    r.x = xv.x + (bf16f(p0[0]) + bf16f(p1[0]) + bf16f(p2[0]) + bf16f(p3[0])) * inv;
    r.y = xv.y + (bf16f(p0[1]) + bf16f(p1[1]) + bf16f(p2[1]) + bf16f(p3[1])) * inv;
    r.z = xv.z + (bf16f(p0[2]) + bf16f(p1[2]) + bf16f(p2[2]) + bf16f(p3[2])) * inv;
    r.w = xv.w + (bf16f(p0[3]) + bf16f(p1[3]) + bf16f(p2[3]) + bf16f(p3[3])) * inv;
    *(float4*)(out + base) = r;
}

// ---------------------------------------------------------------------------
extern "C" void kernel_launch(void* const* d_in, const int* in_sizes, int n_in,
                              void* d_out, int out_size, void* d_ws, size_t ws_size,
                              hipStream_t stream) {
    const float* x  = (const float*)d_in[0];
    const float* Wf = (const float*)d_in[1];
    const float* bf = (const float*)d_in[2];
    const float* Wg = (const float*)d_in[3];
    const float* bg = (const float*)d_in[4];
    const float* Wh = (const float*)d_in[5];
    const float* bh = (const float*)d_in[6];
    float* out = (float*)d_out;

    unsigned char* ws = (unsigned char*)d_ws;
    unsigned short* Wst  = (unsigned short*)(ws);                  // 192 KiB (reserve 256K)
    unsigned short* f16b = (unsigned short*)(ws + 0x040000);       // 1 MiB
    unsigned short* g16b = (unsigned short*)(ws + 0x140000);       // 1 MiB
    unsigned short* hhT  = (unsigned short*)(ws + 0x240000);       // 8.5 MiB tiled
    unsigned short* Ob0  = (unsigned short*)(ws + 0xAC0000);       // 8 MiB bf16 partial
    unsigned short* Ob1  = (unsigned short*)(ws + 0x12C0000);      // 8 MiB
    unsigned short* Ob2  = (unsigned short*)(ws + 0x1AC0000);      // 8 MiB
    unsigned short* Ob3  = (unsigned short*)(ws + 0x22C0000);      // 8 MiB
    float*          lbuf = (float*)(ws + 0x2AC0000);               // 256 KiB

    prep_kernel<<<384, 256, 0, stream>>>(Wf, Wg, Wh, Wst);
    proj_kernel<<<512, 256, 0, stream>>>(x, bf, bg, bh, Wst, f16b, g16b, hhT);
    attn_kernel<<<1024, 256, 0, stream>>>(g16b, f16b, hhT, Ob0, Ob1, Ob2, Ob3, lbuf);
    reduce_kernel<<<4096, 256, 0, stream>>>(x, Ob0, Ob1, Ob2, Ob3, lbuf, out);
}

// Round 13
// 148.107 us; speedup vs baseline: 1.0943x; 1.0943x over previous
//
#include <hip/hip_runtime.h>
#include <hip/hip_bf16.h>
#include <stdint.h>

// Problem constants (B,H,W,C = 4,64,64,256)
#define NN 4096        // H*W
#define CC 256
#define DD 32          // C/8
#define CHW 17408      // u16 per hhT chunk: 2(ks) * 17(ct) * 64(lane) * 8(j)
#define NCT 9          // staged ct tiles per channel-split: 8 channel tiles + ones

typedef short    bf16x8 __attribute__((ext_vector_type(8)));
typedef _Float16 f16x8  __attribute__((ext_vector_type(8)));
typedef float    f32x4  __attribute__((ext_vector_type(4)));

__device__ __forceinline__ unsigned short bf16_rne(float x) {
    union { float f; unsigned int u; } v; v.f = x;
    unsigned int u = v.u;
    return (unsigned short)((u + 0x7FFFu + ((u >> 16) & 1u)) >> 16);
}
__device__ __forceinline__ float bf16f(unsigned short h) {
    union { float f; unsigned int u; } v; v.u = ((unsigned int)h) << 16; return v.f;
}
__device__ __forceinline__ unsigned short f16_bits(float x) {
    union { _Float16 h; unsigned short u; } v; v.h = (_Float16)x;
    return v.u;
}
// hardware packed f32->bf16 RNE convert (no builtin on gfx950; T12 recipe)
__device__ __forceinline__ unsigned int cvt_pk_bf16(float lo, float hi) {
    unsigned int r;
    asm("v_cvt_pk_bf16_f32 %0, %1, %2" : "=v"(r) : "v"(lo), "v"(hi));
    return r;
}
// async global->LDS, 16B per lane; LDS dest = wave-uniform base + lane*16
__device__ __forceinline__ void load_lds16(const unsigned short* g, unsigned short* l) {
    __builtin_amdgcn_global_load_lds(
        (const __attribute__((address_space(1))) unsigned int*)g,
        (__attribute__((address_space(3))) unsigned int*)l, 16, 0, 0);
}

// ---------------------------------------------------------------------------
// Kernel 0: pre-convert weights to bf16, chunk-tiled Wst[ks(8)][row(384)][k(32)].
// rows 0..255 = Wh col (hi), 256..319 = Wf/Wg hi, 320..383 = Wf/Wg lo.
// ---------------------------------------------------------------------------
__global__ __launch_bounds__(256) void prep_kernel(
    const float* __restrict__ Wf, const float* __restrict__ Wg,
    const float* __restrict__ Wh, unsigned short* __restrict__ Wst)
{
    int id  = blockIdx.x * 256 + threadIdx.x;   // grid 384 -> 98304
    int ks  = id / 12288;
    int rem = id - ks * 12288;
    int row = rem >> 5;
    int k   = ks * 32 + (rem & 31);
    unsigned short outv;
    if (row < 256) {
        outv = bf16_rne(Wh[(size_t)k * CC + row]);
    } else if (row < 320) {
        int d = row - 256;
        float v = (d < 32) ? Wf[(size_t)k * DD + d] : Wg[(size_t)k * DD + (d - 32)];
        outv = bf16_rne(v);
    } else {
        int d = row - 320;
        float v = (d < 32) ? Wf[(size_t)k * DD + d] : Wg[(size_t)k * DD + (d - 32)];
        unsigned short h = bf16_rne(v);
        outv = bf16_rne(v - bf16f(h));
    }
    Wst[id] = outv;
}

// ---------------------------------------------------------------------------
// Kernel 1: MFMA projections -- REVERTED to the R9 LDS-staging version
// (fastest passing variant). R10/R11/R12 established: direct-global W reads
// are value-correct but ~10us SLOWER (per-t L2 loads sit in the MFMA dep
// chain; the cooperative global_load_lds DMA queue + single drain wins), and
// the barrier-free restructure mis-executes (NaN) for reasons not visible at
// source level. Do not touch proj again without disasm.
// hhT stored per-chunk in MFMA B-fragment order [b][kc][ks(2)][ct(17)][lane][j];
// f/g written as fp16 [tok][32].
// ---------------------------------------------------------------------------
__global__ __launch_bounds__(256, 2) void proj_kernel(
    const float* __restrict__ x,
    const float* __restrict__ bfv, const float* __restrict__ bgv,
    const float* __restrict__ bhv,
    const unsigned short* __restrict__ Wst,
    unsigned short* __restrict__ f16b, unsigned short* __restrict__ g16b,
    unsigned short* __restrict__ hhT)
{
    const int tid  = threadIdx.x;
    const int lane = tid & 63;
    const int wv   = tid >> 6;
    const int col  = lane & 15;
    const int quad = lane >> 4;
    const int tok0 = blockIdx.x * 32;      // 32 | 4096 -> no batch straddle
    const int b    = tok0 >> 12;

    __shared__ __align__(16) unsigned short xh[32 * 272];   // pitch 272 u16 (544B)
    __shared__ __align__(16) unsigned short xl[32 * 272];
    __shared__ __align__(16) unsigned short WT[1920 * 8];   // [row(384)][40 u16] = 80B pitch

    // ---- stage x (hi/lo) ----
    #pragma unroll
    for (int it = 0; it < 8; ++it) {
        int idx = it * 1024 + tid * 4;
        float4 v = *(const float4*)(x + (size_t)tok0 * CC + idx);
        int tok = idx >> 8, k = idx & 255;
        unsigned short h0 = bf16_rne(v.x), h1 = bf16_rne(v.y),
                       h2 = bf16_rne(v.z), h3 = bf16_rne(v.w);
        uint2 wh_, wl_;
        wh_.x = (unsigned int)h0 | ((unsigned int)h1 << 16);
        wh_.y = (unsigned int)h2 | ((unsigned int)h3 << 16);
        wl_.x = (unsigned int)bf16_rne(v.x - bf16f(h0)) |
                ((unsigned int)bf16_rne(v.y - bf16f(h1)) << 16);
        wl_.y = (unsigned int)bf16_rne(v.z - bf16f(h2)) |
                ((unsigned int)bf16_rne(v.w - bf16f(h3)) << 16);
        *(uint2*)&xh[tok * 272 + k] = wh_;
        *(uint2*)&xl[tok * 272 + k] = wl_;
    }

    // ---- acc init with bias ----
    f32x4 acc[5][2];
    #pragma unroll
    for (int t = 0; t < 5; ++t) {
        int tl = wv * 5 + t;
        float bias;
        if (tl < 16) bias = bhv[tl * 16 + col];
        else { int fd = (tl - 16) * 16 + col;
               bias = (fd < 32) ? bfv[fd] : bgv[fd - 32]; }
        acc[t][0] = (f32x4){bias, bias, bias, bias};
        acc[t][1] = (f32x4){bias, bias, bias, bias};
    }

    for (int ks = 0; ks < 8; ++ks) {
        // ---- stage W chunk: 384 rows x 64B, 5 slots/row (4 real + 1 pad) ----
        for (int t = 0; t < 8; ++t) {
            int i = wv + t * 4;
            if (i >= 30) break;
            int l = i * 64 + lane;          // 0..1919
            int row = l / 5, g = l - row * 5;
            const unsigned short* gp = (g < 4)
                ? (Wst + (size_t)ks * 12288 + row * 32 + g * 8)
                : (Wst + (size_t)ks * 12288);
            load_lds16(gp, &WT[i * 512]);
        }
        __syncthreads();   // W (and x on ks==0) ready

        // ---- A fragments from LDS ----
        bf16x8 ah[2], al[2];
        #pragma unroll
        for (int mt = 0; mt < 2; ++mt) {
            ah[mt] = *(const bf16x8*)&xh[(mt * 16 + col) * 272 + ks * 32 + quad * 8];
            al[mt] = *(const bf16x8*)&xl[(mt * 16 + col) * 272 + ks * 32 + quad * 8];
        }

        #pragma unroll
        for (int t = 0; t < 5; ++t) {
            int tl = wv * 5 + t;
            int wrow = (tl < 16) ? (tl * 16 + col) : (256 + (tl - 16) * 16 + col);
            bf16x8 bh = *(const bf16x8*)&WT[wrow * 40 + quad * 8];
            #pragma unroll
            for (int mt = 0; mt < 2; ++mt) {
                acc[t][mt] = __builtin_amdgcn_mfma_f32_16x16x32_bf16(ah[mt], bh, acc[t][mt], 0, 0, 0);
                acc[t][mt] = __builtin_amdgcn_mfma_f32_16x16x32_bf16(al[mt], bh, acc[t][mt], 0, 0, 0);
            }
            if (tl >= 16) {   // wave-uniform
                bf16x8 bl = *(const bf16x8*)&WT[(wrow + 64) * 40 + quad * 8];
                #pragma unroll
                for (int mt = 0; mt < 2; ++mt)
                    acc[t][mt] = __builtin_amdgcn_mfma_f32_16x16x32_bf16(ah[mt], bl, acc[t][mt], 0, 0, 0);
            }
        }
        __syncthreads();   // before next stage overwrites WT
    }

    // ---- epilogue (fragment-order hhT writes; f/g as fp16) ----
    const int ks_h = (tok0 & 63) >> 5;       // 0 or 1
    const int kc   = (tok0 & 4095) >> 6;
    const size_t tbase = ((size_t)(b * 64 + kc)) * CHW;
    #pragma unroll
    for (int t = 0; t < 5; ++t) {
        int tl = wv * 5 + t;
        if (tl < 16) {
            #pragma unroll
            for (int mt = 0; mt < 2; ++mt) {
                int qk = mt * 2 + (quad >> 1);
                int jb = (quad & 1) * 4;
                uint2 w;
                w.x = (unsigned int)bf16_rne(acc[t][mt][0]) | ((unsigned int)bf16_rne(acc[t][mt][1]) << 16);
                w.y = (unsigned int)bf16_rne(acc[t][mt][2]) | ((unsigned int)bf16_rne(acc[t][mt][3]) << 16);
                *(uint2*)&hhT[tbase + (size_t)(((ks_h * 17 + tl) * 64) + qk * 16 + col) * 8 + jb] = w;
            }
        } else {
            int fd = (tl - 16) * 16 + col;
            unsigned short* dst = (fd < 32) ? f16b : g16b;
            int d = fd & 31;
            #pragma unroll
            for (int mt = 0; mt < 2; ++mt)
                #pragma unroll
                for (int r = 0; r < 4; ++r) {
                    int tok = tok0 + mt * 16 + quad * 4 + r;
                    dst[(size_t)tok * DD + d] = f16_bits(acc[t][mt][r]);
                }
        }
    }
    // ones-tile (ct=16): channel 256+ck -> 1.0 iff ck==0; this block's ks half
    #pragma unroll
    for (int it = 0; it < 2; ++it) {
        int e = tid + it * 256;              // 512 entries: [qk(4)][ck(16)][j(8)]
        int j = e & 7, ck = (e >> 3) & 15, qk = e >> 7;
        hhT[tbase + (size_t)(((ks_h * 17 + 16) * 64) + qk * 16 + ck) * 8 + j] =
            (ck == 0) ? (unsigned short)0x3F80 : (unsigned short)0;
    }
}

// ---------------------------------------------------------------------------
// Kernel 2: fused attention (UNCHANGED from R9 -- last-known-good).
// Fixed-max softmax (M=40), 4-way split-K x 2-way channel split, 1024 blocks.
// 32-key half-steps, counted vmcnt(3|2) + sched_barrier fences, in-register P
// (swapped QK^T + key permutation), hw cvt_pk, -40 folded into QK C-init,
// setprio'd PV, bf16 partial-O.
// ---------------------------------------------------------------------------
__global__ __launch_bounds__(256, 4) void attn_kernel(
    const unsigned short* __restrict__ g16b,
    const unsigned short* __restrict__ f16b,
    const unsigned short* __restrict__ hhT,    // [b][kc][ks][ct][lane][j]
    unsigned short* __restrict__ Ob0,          // bf16 partials [B*NN][CC]
    unsigned short* __restrict__ Ob1,
    unsigned short* __restrict__ Ob2,
    unsigned short* __restrict__ Ob3,
    float* __restrict__ lbuf)                  // [4][B*NN]
{
    const int tid  = threadIdx.x;
    const int lane = tid & 63;
    const int wv   = tid >> 6;             // 0..3
    const int col  = lane & 15;
    const int quad = lane >> 4;
    const int bid  = blockIdx.x;
    const int csp  = bid & 1;              // channel split 0..1
    const int sp   = (bid >> 1) & 3;       // key split 0..3
    const int b    = (bid >> 3) & 3;       // batch
    const int qblk = bid >> 5;             // 0..31
    const int q0   = qblk * 128 + wv * 32; // wave's 32-query base
    const int kcb  = sp * 16;              // this split's chunk range

    __shared__ __align__(16) unsigned short hbuf[2][NCT * 512];  // 2 x 9 KiB

    const unsigned short* fb16 = f16b + (size_t)b * NN * DD;
    const unsigned short* hb   = hhT + (size_t)b * 64 * CHW;

    f16x8 a_g[2];
    #pragma unroll
    for (int a = 0; a < 2; ++a)
        a_g[a] = *(const f16x8*)(g16b + ((size_t)(b * NN + q0 + a * 16 + col)) * DD + quad * 8);

    // permuted key offset within a 32-key half-step for the f A-fragment:
    // M-slot col of tile ktl holds key (col>>2)*8 + ktl*4 + (col&3)
    const int kpermu = (col >> 2) * 8 + (col & 3);

    const f32x4 m40 = {-40.f, -40.f, -40.f, -40.f};   // folded softmax shift
    f32x4 acc[2][NCT];
    #pragma unroll
    for (int a = 0; a < 2; ++a)
        #pragma unroll
        for (int i = 0; i < NCT; ++i) acc[a][i] = (f32x4){0.f, 0.f, 0.f, 0.f};

    // ---- stage half-step 0 (chunk kcb, key-half 0): 9 ct slots over 4 waves ----
    {
        const unsigned short* tile = hb + (size_t)kcb * CHW;   // ks = 0
        #pragma unroll
        for (int t = 0; t < 3; ++t) {
            int s = wv + t * 4;
            if (s >= NCT) break;
            int ct = (s < 8) ? (csp * 8 + s) : 16;
            load_lds16(tile + (size_t)ct * 512 + lane * 8, &hbuf[0][s * 512]);
        }
    }
    __syncthreads();   // prologue: full drain once (buf0 ready)

    // 16 chunks x 2 key-halves = 32 half-steps of 32 keys each
    for (int hs = 0; hs < 32; ++hs) {
        const int nb = hs & 1;

        // ---- async stage next half-step into other buffer ----
        if (hs + 1 < 32) {
            const int kc = kcb + ((hs + 1) >> 1);
            const int ks = (hs + 1) & 1;
            const unsigned short* tile = hb + (size_t)kc * CHW + (size_t)(ks * 17) * 512;
            #pragma unroll
            for (int t = 0; t < 3; ++t) {
                int s = wv + t * 4;
                if (s >= NCT) break;
                int ct = (s < 8) ? (csp * 8 + s) : 16;
                load_lds16(tile + (size_t)ct * 512 + lane * 8, &hbuf[nb ^ 1][s * 512]);
            }
        }

        const int kk0 = kcb * 64 + hs * 32;   // this half-step's 32-key base

        // ---- QK^T swapped (fp16), C-init = -40: C[key-slot][query]; keys
        //      permuted so lane (quad,col) gets keys quad*8+ktl*4+r, query col ----
        f32x4 s_t[2][2];
        #pragma unroll
        for (int ktl = 0; ktl < 2; ++ktl) {
            f16x8 af_ = *(const f16x8*)(fb16 +
                (size_t)(kk0 + kpermu + ktl * 4) * DD + quad * 8);
            #pragma unroll
            for (int a = 0; a < 2; ++a)
                s_t[ktl][a] = __builtin_amdgcn_mfma_f32_16x16x32_f16(af_, a_g[a], m40, 0, 0, 0);
        }

        // ---- p = exp(s): hw-packed f32->bf16, PV A-frags in-register ----
        bf16x8 a_p[2];
        #pragma unroll
        for (int a = 0; a < 2; ++a) {
            union { unsigned int u[4]; bf16x8 v; } cv;
            #pragma unroll
            for (int ktl = 0; ktl < 2; ++ktl) {
                float e0 = __expf(s_t[ktl][a][0]);
                float e1 = __expf(s_t[ktl][a][1]);
                float e2 = __expf(s_t[ktl][a][2]);
                float e3 = __expf(s_t[ktl][a][3]);
                cv.u[ktl * 2 + 0] = cvt_pk_bf16(e0, e1);
                cv.u[ktl * 2 + 1] = cvt_pk_bf16(e2, e3);
            }
            a_p[a] = cv.v;
        }

        // ---- barrier #1: previous stage retired in every wave; this hs's
        //      prefetch (3 loads wv0 / 2 loads wv1-3) stays outstanding ----
        __builtin_amdgcn_sched_barrier(0);
        if (wv == 0) asm volatile("s_waitcnt vmcnt(3)" ::: "memory");
        else         asm volatile("s_waitcnt vmcnt(2)" ::: "memory");
        __builtin_amdgcn_s_barrier();
        __builtin_amdgcn_sched_barrier(0);

        // ---- PV over this csp's 9 staged ct tiles; B-frag feeds both atiles ----
        __builtin_amdgcn_s_setprio(1);
        #pragma unroll
        for (int s = 0; s < NCT; ++s) {
            bf16x8 bh = *(const bf16x8*)&hbuf[nb][(s * 64 + lane) * 8];
            acc[0][s] = __builtin_amdgcn_mfma_f32_16x16x32_bf16(a_p[0], bh, acc[0][s], 0, 0, 0);
            acc[1][s] = __builtin_amdgcn_mfma_f32_16x16x32_bf16(a_p[1], bh, acc[1][s], 0, 0, 0);
        }
        __builtin_amdgcn_s_setprio(0);

        // ---- barrier #2: overwrite guard for the buffer re-staged next iter ----
        __builtin_amdgcn_sched_barrier(0);
        __builtin_amdgcn_s_barrier();
        __builtin_amdgcn_sched_barrier(0);
    }

    // ---- epilogue: store bf16 partial O (this csp's 128 channels) and l ----
    unsigned short* Obufs[4] = {Ob0, Ob1, Ob2, Ob3};
    unsigned short* Op = Obufs[sp];
    #pragma unroll
    for (int a = 0; a < 2; ++a) {
        const size_t obase = (size_t)(b * NN + q0 + a * 16) * CC;
        #pragma unroll
        for (int s = 0; s < 8; ++s) {
            const int ch = (csp * 8 + s) * 16 + col;
            #pragma unroll
            for (int r = 0; r < 4; ++r)
                Op[obase + (size_t)(quad * 4 + r) * CC + ch] = bf16_rne(acc[a][s][r]);
        }
        if (csp == 0 && col == 0) {   // l from the ones tile; csp0 owns it
            #pragma unroll
            for (int r = 0; r < 4; ++r)
                lbuf[sp * (4 * NN) + b * NN + q0 + a * 16 + quad * 4 + r] = acc[a][8][r];
        }
    }
}

// ---------------------------------------------------------------------------
// Kernel 3: out = x + (Ob0+Ob1+Ob2+Ob3) / (l0+l1+l2+l3).  bf16 partials.
// NEW this round (G13 widen): 8 channels/thread -- partials load as uint4
// (16B/lane, the coalescing sweet spot) instead of u16x4 (8B/lane); grid
// halves to 2048; lbuf's 4 scalar reads amortize over 2x elements. Per-
// element math and addition order unchanged -> bit-identical output.
// ---------------------------------------------------------------------------
__global__ __launch_bounds__(256) void reduce_kernel(
    const float* __restrict__ x,
    const unsigned short* __restrict__ Ob0, const unsigned short* __restrict__ Ob1,
    const unsigned short* __restrict__ Ob2, const unsigned short* __restrict__ Ob3,
    const float* __restrict__ lbuf, float* __restrict__ out)
{
    int id = blockIdx.x * 256 + threadIdx.x;   // grid 2048 -> 524288
    int q  = id >> 5;                          // token row (B*NN); 32 thr/row
    int c8 = (id & 31) * 8;
    size_t base = (size_t)q * CC + c8;
    float inv = 1.0f / (lbuf[q] + lbuf[4 * NN + q] + lbuf[8 * NN + q] + lbuf[12 * NN + q]);
    uint4 u0 = *(const uint4*)(Ob0 + base);    // 8 bf16 per buffer
    uint4 u1 = *(const uint4*)(Ob1 + base);
    uint4 u2 = *(const uint4*)(Ob2 + base);
    uint4 u3 = *(const uint4*)(Ob3 + base);
    float4 xa = *(const float4*)(x + base);
    float4 xb = *(const float4*)(x + base + 4);
    float s[8];
    #pragma unroll
    for (int i = 0; i < 4; ++i) {
        unsigned int w0 = ((const unsigned int*)&u0)[i];
        unsigned int w1 = ((const unsigned int*)&u1)[i];
        unsigned int w2 = ((const unsigned int*)&u2)[i];
        unsigned int w3 = ((const unsigned int*)&u3)[i];
        s[2 * i]     = bf16f((unsigned short)w0) + bf16f((unsigned short)w1)
                     + bf16f((unsigned short)w2) + bf16f((unsigned short)w3);
        s[2 * i + 1] = bf16f((unsigned short)(w0 >> 16)) + bf16f((unsigned short)(w1 >> 16))
                     + bf16f((unsigned short)(w2 >> 16)) + bf16f((unsigned short)(w3 >> 16));
    }
    float4 ra, rb;
    ra.x = xa.x + s[0] * inv;
    ra.y = xa.y + s[1] * inv;
    ra.z = xa.z + s[2] * inv;
    ra.w = xa.w + s[3] * inv;
    rb.x = xb.x + s[4] * inv;
    rb.y = xb.y + s[5] * inv;
    rb.z = xb.z + s[6] * inv;
    rb.w = xb.w + s[7] * inv;
    *(float4*)(out + base) = ra;
    *(float4*)(out + base + 4) = rb;
}

// ---------------------------------------------------------------------------
extern "C" void kernel_launch(void* const* d_in, const int* in_sizes, int n_in,
                              void* d_out, int out_size, void* d_ws, size_t ws_size,
                              hipStream_t stream) {
    const float* x  = (const float*)d_in[0];
    const float* Wf = (const float*)d_in[1];
    const float* bf = (const float*)d_in[2];
    const float* Wg = (const float*)d_in[3];
    const float* bg = (const float*)d_in[4];
    const float* Wh = (const float*)d_in[5];
    const float* bh = (const float*)d_in[6];
    float* out = (float*)d_out;

    unsigned char* ws = (unsigned char*)d_ws;
    unsigned short* Wst  = (unsigned short*)(ws);                  // 192 KiB (reserve 256K)
    unsigned short* f16b = (unsigned short*)(ws + 0x040000);       // 1 MiB
    unsigned short* g16b = (unsigned short*)(ws + 0x140000);       // 1 MiB
    unsigned short* hhT  = (unsigned short*)(ws + 0x240000);       // 8.5 MiB tiled
    unsigned short* Ob0  = (unsigned short*)(ws + 0xAC0000);       // 8 MiB bf16 partial
    unsigned short* Ob1  = (unsigned short*)(ws + 0x12C0000);      // 8 MiB
    unsigned short* Ob2  = (unsigned short*)(ws + 0x1AC0000);      // 8 MiB
    unsigned short* Ob3  = (unsigned short*)(ws + 0x22C0000);      // 8 MiB
    float*          lbuf = (float*)(ws + 0x2AC0000);               // 256 KiB

    prep_kernel<<<384, 256, 0, stream>>>(Wf, Wg, Wh, Wst);
    proj_kernel<<<512, 256, 0, stream>>>(x, bf, bg, bh, Wst, f16b, g16b, hhT);
    attn_kernel<<<1024, 256, 0, stream>>>(g16b, f16b, hhT, Ob0, Ob1, Ob2, Ob3, lbuf);
    reduce_kernel<<<2048, 256, 0, stream>>>(x, Ob0, Ob1, Ob2, Ob3, lbuf, out);
}

// Round 14
// 141.941 us; speedup vs baseline: 1.1418x; 1.0434x over previous
//
#include <hip/hip_runtime.h>
#include <hip/hip_bf16.h>
#include <stdint.h>

// Problem constants (B,H,W,C = 4,64,64,256)
#define NN 4096        // H*W
#define CC 256
#define DD 32          // C/8
#define CHW 17408      // u16 per hhT chunk: 2(ks) * 17(ct) * 64(lane) * 8(j)

typedef short    bf16x8 __attribute__((ext_vector_type(8)));
typedef _Float16 f16x8  __attribute__((ext_vector_type(8)));
typedef float    f32x4  __attribute__((ext_vector_type(4)));

__device__ __forceinline__ unsigned short bf16_rne(float x) {
    union { float f; unsigned int u; } v; v.f = x;
    unsigned int u = v.u;
    return (unsigned short)((u + 0x7FFFu + ((u >> 16) & 1u)) >> 16);
}
__device__ __forceinline__ float bf16f(unsigned short h) {
    union { float f; unsigned int u; } v; v.u = ((unsigned int)h) << 16; return v.f;
}
__device__ __forceinline__ unsigned short f16_bits(float x) {
    union { _Float16 h; unsigned short u; } v; v.h = (_Float16)x;
    return v.u;
}
// hardware packed f32->bf16 RNE convert (no builtin on gfx950; T12 recipe)
__device__ __forceinline__ unsigned int cvt_pk_bf16(float lo, float hi) {
    unsigned int r;
    asm("v_cvt_pk_bf16_f32 %0, %1, %2" : "=v"(r) : "v"(lo), "v"(hi));
    return r;
}
// async global->LDS, 16B per lane; LDS dest = wave-uniform base + lane*16
__device__ __forceinline__ void load_lds16(const unsigned short* g, unsigned short* l) {
    __builtin_amdgcn_global_load_lds(
        (const __attribute__((address_space(1))) unsigned int*)g,
        (__attribute__((address_space(3))) unsigned int*)l, 16, 0, 0);
}

// ---------------------------------------------------------------------------
// Kernel 0: pre-convert weights to bf16, chunk-tiled Wst[ks(8)][row(384)][k(32)].
// rows 0..255 = Wh col (hi), 256..319 = Wf/Wg hi, 320..383 = Wf/Wg lo.
// ---------------------------------------------------------------------------
__global__ __launch_bounds__(256) void prep_kernel(
    const float* __restrict__ Wf, const float* __restrict__ Wg,
    const float* __restrict__ Wh, unsigned short* __restrict__ Wst)
{
    int id  = blockIdx.x * 256 + threadIdx.x;   // grid 384 -> 98304
    int ks  = id / 12288;
    int rem = id - ks * 12288;
    int row = rem >> 5;
    int k   = ks * 32 + (rem & 31);
    unsigned short outv;
    if (row < 256) {
        outv = bf16_rne(Wh[(size_t)k * CC + row]);
    } else if (row < 320) {
        int d = row - 256;
        float v = (d < 32) ? Wf[(size_t)k * DD + d] : Wg[(size_t)k * DD + (d - 32)];
        outv = bf16_rne(v);
    } else {
        int d = row - 320;
        float v = (d < 32) ? Wf[(size_t)k * DD + d] : Wg[(size_t)k * DD + (d - 32)];
        unsigned short h = bf16_rne(v);
        outv = bf16_rne(v - bf16f(h));
    }
    Wst[id] = outv;
}

// ---------------------------------------------------------------------------
// Kernel 1: MFMA projections (R9 LDS-staging version -- fastest passing;
// direct-global W was slower (R12), restructure NaN'd (R10). Frozen.)
// hhT stored per-chunk in MFMA B-fragment order [b][kc][ks(2)][ct(17)][lane][j];
// f/g written as fp16 [tok][32].
// ---------------------------------------------------------------------------
__global__ __launch_bounds__(256, 2) void proj_kernel(
    const float* __restrict__ x,
    const float* __restrict__ bfv, const float* __restrict__ bgv,
    const float* __restrict__ bhv,
    const unsigned short* __restrict__ Wst,
    unsigned short* __restrict__ f16b, unsigned short* __restrict__ g16b,
    unsigned short* __restrict__ hhT)
{
    const int tid  = threadIdx.x;
    const int lane = tid & 63;
    const int wv   = tid >> 6;
    const int col  = lane & 15;
    const int quad = lane >> 4;
    const int tok0 = blockIdx.x * 32;      // 32 | 4096 -> no batch straddle
    const int b    = tok0 >> 12;

    __shared__ __align__(16) unsigned short xh[32 * 272];   // pitch 272 u16 (544B)
    __shared__ __align__(16) unsigned short xl[32 * 272];
    __shared__ __align__(16) unsigned short WT[1920 * 8];   // [row(384)][40 u16] = 80B pitch

    // ---- stage x (hi/lo) ----
    #pragma unroll
    for (int it = 0; it < 8; ++it) {
        int idx = it * 1024 + tid * 4;
        float4 v = *(const float4*)(x + (size_t)tok0 * CC + idx);
        int tok = idx >> 8, k = idx & 255;
        unsigned short h0 = bf16_rne(v.x), h1 = bf16_rne(v.y),
                       h2 = bf16_rne(v.z), h3 = bf16_rne(v.w);
        uint2 wh_, wl_;
        wh_.x = (unsigned int)h0 | ((unsigned int)h1 << 16);
        wh_.y = (unsigned int)h2 | ((unsigned int)h3 << 16);
        wl_.x = (unsigned int)bf16_rne(v.x - bf16f(h0)) |
                ((unsigned int)bf16_rne(v.y - bf16f(h1)) << 16);
        wl_.y = (unsigned int)bf16_rne(v.z - bf16f(h2)) |
                ((unsigned int)bf16_rne(v.w - bf16f(h3)) << 16);
        *(uint2*)&xh[tok * 272 + k] = wh_;
        *(uint2*)&xl[tok * 272 + k] = wl_;
    }

    // ---- acc init with bias ----
    f32x4 acc[5][2];
    #pragma unroll
    for (int t = 0; t < 5; ++t) {
        int tl = wv * 5 + t;
        float bias;
        if (tl < 16) bias = bhv[tl * 16 + col];
        else { int fd = (tl - 16) * 16 + col;
               bias = (fd < 32) ? bfv[fd] : bgv[fd - 32]; }
        acc[t][0] = (f32x4){bias, bias, bias, bias};
        acc[t][1] = (f32x4){bias, bias, bias, bias};
    }

    for (int ks = 0; ks < 8; ++ks) {
        // ---- stage W chunk: 384 rows x 64B, 5 slots/row (4 real + 1 pad) ----
        for (int t = 0; t < 8; ++t) {
            int i = wv + t * 4;
            if (i >= 30) break;
            int l = i * 64 + lane;          // 0..1919
            int row = l / 5, g = l - row * 5;
            const unsigned short* gp = (g < 4)
                ? (Wst + (size_t)ks * 12288 + row * 32 + g * 8)
                : (Wst + (size_t)ks * 12288);
            load_lds16(gp, &WT[i * 512]);
        }
        __syncthreads();   // W (and x on ks==0) ready

        // ---- A fragments from LDS ----
        bf16x8 ah[2], al[2];
        #pragma unroll
        for (int mt = 0; mt < 2; ++mt) {
            ah[mt] = *(const bf16x8*)&xh[(mt * 16 + col) * 272 + ks * 32 + quad * 8];
            al[mt] = *(const bf16x8*)&xl[(mt * 16 + col) * 272 + ks * 32 + quad * 8];
        }

        #pragma unroll
        for (int t = 0; t < 5; ++t) {
            int tl = wv * 5 + t;
            int wrow = (tl < 16) ? (tl * 16 + col) : (256 + (tl - 16) * 16 + col);
            bf16x8 bh = *(const bf16x8*)&WT[wrow * 40 + quad * 8];
            #pragma unroll
            for (int mt = 0; mt < 2; ++mt) {
                acc[t][mt] = __builtin_amdgcn_mfma_f32_16x16x32_bf16(ah[mt], bh, acc[t][mt], 0, 0, 0);
                acc[t][mt] = __builtin_amdgcn_mfma_f32_16x16x32_bf16(al[mt], bh, acc[t][mt], 0, 0, 0);
            }
            if (tl >= 16) {   // wave-uniform
                bf16x8 bl = *(const bf16x8*)&WT[(wrow + 64) * 40 + quad * 8];
                #pragma unroll
                for (int mt = 0; mt < 2; ++mt)
                    acc[t][mt] = __builtin_amdgcn_mfma_f32_16x16x32_bf16(ah[mt], bl, acc[t][mt], 0, 0, 0);
            }
        }
        __syncthreads();   // before next stage overwrites WT
    }

    // ---- epilogue (fragment-order hhT writes; f/g as fp16) ----
    const int ks_h = (tok0 & 63) >> 5;       // 0 or 1
    const int kc   = (tok0 & 4095) >> 6;
    const size_t tbase = ((size_t)(b * 64 + kc)) * CHW;
    #pragma unroll
    for (int t = 0; t < 5; ++t) {
        int tl = wv * 5 + t;
        if (tl < 16) {
            #pragma unroll
            for (int mt = 0; mt < 2; ++mt) {
                int qk = mt * 2 + (quad >> 1);
                int jb = (quad & 1) * 4;
                uint2 w;
                w.x = (unsigned int)bf16_rne(acc[t][mt][0]) | ((unsigned int)bf16_rne(acc[t][mt][1]) << 16);
                w.y = (unsigned int)bf16_rne(acc[t][mt][2]) | ((unsigned int)bf16_rne(acc[t][mt][3]) << 16);
                *(uint2*)&hhT[tbase + (size_t)(((ks_h * 17 + tl) * 64) + qk * 16 + col) * 8 + jb] = w;
            }
        } else {
            int fd = (tl - 16) * 16 + col;
            unsigned short* dst = (fd < 32) ? f16b : g16b;
            int d = fd & 31;
            #pragma unroll
            for (int mt = 0; mt < 2; ++mt)
                #pragma unroll
                for (int r = 0; r < 4; ++r) {
                    int tok = tok0 + mt * 16 + quad * 4 + r;
                    dst[(size_t)tok * DD + d] = f16_bits(acc[t][mt][r]);
                }
        }
    }
    // ones-tile (ct=16): channel 256+ck -> 1.0 iff ck==0; this block's ks half
    #pragma unroll
    for (int it = 0; it < 2; ++it) {
        int e = tid + it * 256;              // 512 entries: [qk(4)][ck(16)][j(8)]
        int j = e & 7, ck = (e >> 3) & 15, qk = e >> 7;
        hhT[tbase + (size_t)(((ks_h * 17 + 16) * 64) + qk * 16 + ck) * 8 + j] =
            (ck == 0) ? (unsigned short)0x3F80 : (unsigned short)0;
    }
}

// ---------------------------------------------------------------------------
// Kernel 2: fused attention, fixed-max softmax (M=40), 4-way split-K only --
// csp channel split REMOVED this round (it duplicated QK^T, exp, af loads
// and hhT staging across block pairs; the p_lds path it bought occupancy to
// hide was deleted in R3). 512 blocks (4sp x 4b x 32qblk) x 256 thr.
// Sync skeleton = R0's PROVEN one: stage full 34-slot chunk (IDENTITY source
// mapping), ONE __syncthreads per 64-key chunk (16 barriers vs 64); nothing
// in flight across barriers (compiler's pre-QK FIFO drain + chunk barrier).
// Per-wave: 32 queries x all 17 ct tiles, acc[2][17] (-> launch_bounds 2).
// Banked improvements kept: in-reg P (swapped QK^T + key perm), hw cvt_pk,
// -40 C-init fold, setprio'd PV, bf16 partial-O. Accumulation order per
// acc[a][s] unchanged (half0 then half1 per chunk) -> bit-identical output.
// ---------------------------------------------------------------------------
__global__ __launch_bounds__(256, 2) void attn_kernel(
    const unsigned short* __restrict__ g16b,
    const unsigned short* __restrict__ f16b,
    const unsigned short* __restrict__ hhT,    // [b][kc][ks][ct][lane][j]
    unsigned short* __restrict__ Ob0,          // bf16 partials [B*NN][CC]
    unsigned short* __restrict__ Ob1,
    unsigned short* __restrict__ Ob2,
    unsigned short* __restrict__ Ob3,
    float* __restrict__ lbuf)                  // [4][B*NN]
{
    const int tid  = threadIdx.x;
    const int lane = tid & 63;
    const int wv   = tid >> 6;             // 0..3
    const int col  = lane & 15;
    const int quad = lane >> 4;
    const int bid  = blockIdx.x;
    const int sp   = bid & 3;              // key split 0..3
    const int b    = (bid >> 2) & 3;       // batch
    const int qblk = bid >> 4;             // 0..31
    const int q0   = qblk * 128 + wv * 32; // wave's 32-query base
    const int kcb  = sp * 16;              // this split's chunk range

    __shared__ __align__(16) unsigned short hbuf[2][34 * 512];  // 2 x 34 KiB

    const unsigned short* fb16 = f16b + (size_t)b * NN * DD;
    const unsigned short* hb   = hhT + (size_t)b * 64 * CHW;

    f16x8 a_g[2];
    #pragma unroll
    for (int a = 0; a < 2; ++a)
        a_g[a] = *(const f16x8*)(g16b + ((size_t)(b * NN + q0 + a * 16 + col)) * DD + quad * 8);

    // permuted key offset within a 32-key half for the f A-fragment:
    // M-slot col of tile ktl holds key (col>>2)*8 + ktl*4 + (col&3)
    const int kpermu = (col >> 2) * 8 + (col & 3);

    const f32x4 m40 = {-40.f, -40.f, -40.f, -40.f};   // folded softmax shift
    f32x4 acc[2][17];
    #pragma unroll
    for (int a = 0; a < 2; ++a)
        #pragma unroll
        for (int i = 0; i < 17; ++i) acc[a][i] = (f32x4){0.f, 0.f, 0.f, 0.f};

    // ---- prologue: stage chunk kcb (identity mapping; 34 slots / 4 waves) ----
    {
        const unsigned short* tile = hb + (size_t)kcb * CHW;
        for (int t = 0; t < 9; ++t) {
            int i = wv + t * 4;
            if (i >= 34) break;            // wave-uniform break
            load_lds16(tile + (size_t)(i * 64 + lane) * 8, &hbuf[0][i * 512]);
        }
    }
    __syncthreads();

    for (int kc = 0; kc < 16; ++kc) {
        const int nb = kc & 1;

        // ---- async stage next chunk into other buffer (drained by this
        //      chunk's pre-QK compiler wait; block-wide at chunk barrier) ----
        if (kc + 1 < 16) {
            const unsigned short* tile = hb + (size_t)(kcb + kc + 1) * CHW;
            for (int t = 0; t < 9; ++t) {
                int i = wv + t * 4;
                if (i >= 34) break;
                load_lds16(tile + (size_t)(i * 64 + lane) * 8, &hbuf[nb ^ 1][i * 512]);
            }
        }

        #pragma unroll
        for (int half = 0; half < 2; ++half) {
            const int kk0 = (kcb + kc) * 64 + half * 32;

            // ---- QK^T swapped (fp16), C-init = -40 ----
            f32x4 s_t[2][2];
            #pragma unroll
            for (int ktl = 0; ktl < 2; ++ktl) {
                f16x8 af_ = *(const f16x8*)(fb16 +
                    (size_t)(kk0 + kpermu + ktl * 4) * DD + quad * 8);
                #pragma unroll
                for (int a = 0; a < 2; ++a)
                    s_t[ktl][a] = __builtin_amdgcn_mfma_f32_16x16x32_f16(af_, a_g[a], m40, 0, 0, 0);
            }

            // ---- p = exp(s): hw-packed f32->bf16, PV A-frags in-register ----
            bf16x8 a_p[2];
            #pragma unroll
            for (int a = 0; a < 2; ++a) {
                union { unsigned int u[4]; bf16x8 v; } cv;
                #pragma unroll
                for (int ktl = 0; ktl < 2; ++ktl) {
                    float e0 = __expf(s_t[ktl][a][0]);
                    float e1 = __expf(s_t[ktl][a][1]);
                    float e2 = __expf(s_t[ktl][a][2]);
                    float e3 = __expf(s_t[ktl][a][3]);
                    cv.u[ktl * 2 + 0] = cvt_pk_bf16(e0, e1);
                    cv.u[ktl * 2 + 1] = cvt_pk_bf16(e2, e3);
                }
                a_p[a] = cv.v;
            }

            // ---- PV over all 17 ct tiles of this half; setprio'd cluster ----
            __builtin_amdgcn_s_setprio(1);
            #pragma unroll
            for (int s = 0; s < 17; ++s) {
                bf16x8 bh = *(const bf16x8*)&hbuf[nb][((half * 17 + s) * 64 + lane) * 8];
                acc[0][s] = __builtin_amdgcn_mfma_f32_16x16x32_bf16(a_p[0], bh, acc[0][s], 0, 0, 0);
                acc[1][s] = __builtin_amdgcn_mfma_f32_16x16x32_bf16(a_p[1], bh, acc[1][s], 0, 0, 0);
            }
            __builtin_amdgcn_s_setprio(0);
        }

        __syncthreads();   // R0 skeleton: one barrier per chunk -- drains the
                           // stage (already wave-drained pre-QK) + guards swap
    }

    // ---- epilogue: store bf16 partial O (all 256 channels) and l ----
    unsigned short* Obufs[4] = {Ob0, Ob1, Ob2, Ob3};
    unsigned short* Op = Obufs[sp];
    #pragma unroll
    for (int a = 0; a < 2; ++a) {
        const size_t obase = (size_t)(b * NN + q0 + a * 16) * CC;
        #pragma unroll
        for (int s = 0; s < 16; ++s) {
            const int ch = s * 16 + col;
            #pragma unroll
            for (int r = 0; r < 4; ++r)
                Op[obase + (size_t)(quad * 4 + r) * CC + ch] = bf16_rne(acc[a][s][r]);
        }
        if (col == 0) {   // l from the ones tile
            #pragma unroll
            for (int r = 0; r < 4; ++r)
                lbuf[sp * (4 * NN) + b * NN + q0 + a * 16 + quad * 4 + r] = acc[a][16][r];
        }
    }
}

// ---------------------------------------------------------------------------
// Kernel 3: out = x + (Ob0+Ob1+Ob2+Ob3) / (l0+l1+l2+l3).  bf16 partials,
// 8 channels/thread (uint4 = 16B/lane loads; R13).
// ---------------------------------------------------------------------------
__global__ __launch_bounds__(256) void reduce_kernel(
    const float* __restrict__ x,
    const unsigned short* __restrict__ Ob0, const unsigned short* __restrict__ Ob1,
    const unsigned short* __restrict__ Ob2, const unsigned short* __restrict__ Ob3,
    const float* __restrict__ lbuf, float* __restrict__ out)
{
    int id = blockIdx.x * 256 + threadIdx.x;   // grid 2048 -> 524288
    int q  = id >> 5;                          // token row (B*NN); 32 thr/row
    int c8 = (id & 31) * 8;
    size_t base = (size_t)q * CC + c8;
    float inv = 1.0f / (lbuf[q] + lbuf[4 * NN + q] + lbuf[8 * NN + q] + lbuf[12 * NN + q]);
    uint4 u0 = *(const uint4*)(Ob0 + base);    // 8 bf16 per buffer
    uint4 u1 = *(const uint4*)(Ob1 + base);
    uint4 u2 = *(const uint4*)(Ob2 + base);
    uint4 u3 = *(const uint4*)(Ob3 + base);
    float4 xa = *(const float4*)(x + base);
    float4 xb = *(const float4*)(x + base + 4);
    float s[8];
    #pragma unroll
    for (int i = 0; i < 4; ++i) {
        unsigned int w0 = ((const unsigned int*)&u0)[i];
        unsigned int w1 = ((const unsigned int*)&u1)[i];
        unsigned int w2 = ((const unsigned int*)&u2)[i];
        unsigned int w3 = ((const unsigned int*)&u3)[i];
        s[2 * i]     = bf16f((unsigned short)w0) + bf16f((unsigned short)w1)
                     + bf16f((unsigned short)w2) + bf16f((unsigned short)w3);
        s[2 * i + 1] = bf16f((unsigned short)(w0 >> 16)) + bf16f((unsigned short)(w1 >> 16))
                     + bf16f((unsigned short)(w2 >> 16)) + bf16f((unsigned short)(w3 >> 16));
    }
    float4 ra, rb;
    ra.x = xa.x + s[0] * inv;
    ra.y = xa.y + s[1] * inv;
    ra.z = xa.z + s[2] * inv;
    ra.w = xa.w + s[3] * inv;
    rb.x = xb.x + s[4] * inv;
    rb.y = xb.y + s[5] * inv;
    rb.z = xb.z + s[6] * inv;
    rb.w = xb.w + s[7] * inv;
    *(float4*)(out + base) = ra;
    *(float4*)(out + base + 4) = rb;
}

// ---------------------------------------------------------------------------
extern "C" void kernel_launch(void* const* d_in, const int* in_sizes, int n_in,
                              void* d_out, int out_size, void* d_ws, size_t ws_size,
                              hipStream_t stream) {
    const float* x  = (const float*)d_in[0];
    const float* Wf = (const float*)d_in[1];
    const float* bf = (const float*)d_in[2];
    const float* Wg = (const float*)d_in[3];
    const float* bg = (const float*)d_in[4];
    const float* Wh = (const float*)d_in[5];
    const float* bh = (const float*)d_in[6];
    float* out = (float*)d_out;

    unsigned char* ws = (unsigned char*)d_ws;
    unsigned short* Wst  = (unsigned short*)(ws);                  // 192 KiB (reserve 256K)
    unsigned short* f16b = (unsigned short*)(ws + 0x040000);       // 1 MiB
    unsigned short* g16b = (unsigned short*)(ws + 0x140000);       // 1 MiB
    unsigned short* hhT  = (unsigned short*)(ws + 0x240000);       // 8.5 MiB tiled
    unsigned short* Ob0  = (unsigned short*)(ws + 0xAC0000);       // 8 MiB bf16 partial
    unsigned short* Ob1  = (unsigned short*)(ws + 0x12C0000);      // 8 MiB
    unsigned short* Ob2  = (unsigned short*)(ws + 0x1AC0000);      // 8 MiB
    unsigned short* Ob3  = (unsigned short*)(ws + 0x22C0000);      // 8 MiB
    float*          lbuf = (float*)(ws + 0x2AC0000);               // 256 KiB

    prep_kernel<<<384, 256, 0, stream>>>(Wf, Wg, Wh, Wst);
    proj_kernel<<<512, 256, 0, stream>>>(x, bf, bg, bh, Wst, f16b, g16b, hhT);
    attn_kernel<<<512, 256, 0, stream>>>(g16b, f16b, hhT, Ob0, Ob1, Ob2, Ob3, lbuf);
    reduce_kernel<<<2048, 256, 0, stream>>>(x, Ob0, Ob1, Ob2, Ob3, lbuf, out);
}